// Round 6
// baseline (837.705 us; speedup 1.0000x reference)
//
#include <hip/hip_runtime.h>

typedef __bf16 bf16x4 __attribute__((ext_vector_type(4)));
typedef __bf16 bf16x8 __attribute__((ext_vector_type(8)));
typedef float floatx4 __attribute__((ext_vector_type(4)));

#define MFMA16(a, b, c) __builtin_amdgcn_mfma_f32_16x16x32_bf16((a), (b), (c), 0, 0, 0)

constexpr int D_MODEL = 1024;
constexpr int SEQ = 2048;
constexpr int HEAD_DIM = 64;
constexpr int M_TOK = 2 * SEQ;   // 4096 tokens (B=2)
constexpr int N_HEADS = 16;
constexpr float ROPE_C = 0.20762050593048596f;   // log2(10000)/64
constexpr int LDSP = 40;         // padded LDS row (32+8): 2-way bank pattern = free

// ---------------------------------------------------------------------------
// fp32 -> bf16 conversion prepass (n multiple of 8)
// ---------------------------------------------------------------------------
__global__ __launch_bounds__(256) void f32_to_bf16(const float* __restrict__ s,
                                                   __bf16* __restrict__ d, int n)
{
    const int i = (blockIdx.x * 256 + threadIdx.x) * 8;
    if (i >= n) return;
    const floatx4 lo = *(const floatx4*)(s + i);
    const floatx4 hi = *(const floatx4*)(s + i + 4);
    bf16x8 v;
    v[0] = (__bf16)lo[0]; v[1] = (__bf16)lo[1]; v[2] = (__bf16)lo[2]; v[3] = (__bf16)lo[3];
    v[4] = (__bf16)hi[0]; v[5] = (__bf16)hi[1]; v[6] = (__bf16)hi[2]; v[7] = (__bf16)hi[3];
    *(bf16x8*)(d + i) = v;
}

// ---------------------------------------------------------------------------
// Tiled GEMM: C[M][N] = A[M][1024] . B[N][1024]^T, bf16 in, 128x128 tile,
// 256 threads (4 waves, 2x2 of 64x64), BK=32, LDS-staged (padded rows).
// MODE 0: fused QKV epilogue (N=3072): n<1024 -> Qb (+RoPE), <2048 -> Kb
//         (+RoPE), else V written TRANSPOSED per head: Vt[bh*64+d][token].
// MODE 1: plain fp32 output (out projection).
// ---------------------------------------------------------------------------
template<int MODE>
__global__ __launch_bounds__(256) void gemm_tiled(
    const __bf16* __restrict__ A, const __bf16* __restrict__ B,
    __bf16* __restrict__ Qb, __bf16* __restrict__ Kb, __bf16* __restrict__ Vt,
    float* __restrict__ Cf, const int* __restrict__ tokpos)
{
    __shared__ __bf16 As[128 * LDSP];
    __shared__ __bf16 Bs[128 * LDSP];
    const int tid  = threadIdx.x;
    const int wave = tid >> 6, lane = tid & 63;
    const int quad = lane >> 4, l16 = lane & 15;
    const int m0 = blockIdx.x * 128, n0 = blockIdx.y * 128;
    const int wm = (wave >> 1) * 64, wn = (wave & 1) * 64;

    floatx4 acc[4][4] = {};

    for (int k0 = 0; k0 < D_MODEL; k0 += 32) {
        __syncthreads();   // protect previous iteration's fragment reads
#pragma unroll
        for (int r = 0; r < 2; ++r) {
            const int le = r * 2048 + tid * 8;       // 4096 elems per tile
            const int m = le >> 5, kk = le & 31;     // 4 lanes per 32-elem row
            *(bf16x8*)&As[m * LDSP + kk] =
                *(const bf16x8*)(A + (size_t)(m0 + m) * D_MODEL + k0 + kk);
            *(bf16x8*)&Bs[m * LDSP + kk] =
                *(const bf16x8*)(B + (size_t)(n0 + m) * D_MODEL + k0 + kk);
        }
        __syncthreads();

        bf16x8 af[4], bf[4];
#pragma unroll
        for (int i = 0; i < 4; ++i)
            af[i] = *(const bf16x8*)&As[(wm + i * 16 + l16) * LDSP + quad * 8];
#pragma unroll
        for (int j = 0; j < 4; ++j)
            bf[j] = *(const bf16x8*)&Bs[(wn + j * 16 + l16) * LDSP + quad * 8];
#pragma unroll
        for (int i = 0; i < 4; ++i)
#pragma unroll
            for (int j = 0; j < 4; ++j)
                acc[i][j] = MFMA16(af[i], bf[j], acc[i][j]);
    }

    // ---- epilogue ----
#pragma unroll
    for (int i = 0; i < 4; ++i) {
#pragma unroll
        for (int j = 0; j < 4; ++j) {
            const int n  = n0 + wn + j * 16 + l16;       // region-uniform per (i,j)
            const int t0 = m0 + wm + i * 16 + quad * 4;  // 4 consecutive tokens
            if (MODE == 1) {
#pragma unroll
                for (int r = 0; r < 4; ++r)
                    Cf[(size_t)(t0 + r) * D_MODEL + n] = acc[i][j][r];
            } else {
                const int region = n >> 10, col = n & 1023;
                if (region == 2) {
                    // V transposed: Vt[((b*16+h)*64+d)*SEQ + s]; row = b*1024+col
                    bf16x4 v;
#pragma unroll
                    for (int r = 0; r < 4; ++r) v[r] = (__bf16)acc[i][j][r];
                    const size_t vidx =
                        ((size_t)(t0 >> 11) * 1024 + col) * SEQ + (t0 & (SEQ - 1));
                    *(bf16x4*)(Vt + vidx) = v;
                } else {
                    const int d = col & (HEAD_DIM - 1);
                    const float inv = exp2f(-(float)(d & ~1) * ROPE_C);
                    __bf16* dst = (region == 0) ? Qb : Kb;
#pragma unroll
                    for (int r = 0; r < 4; ++r) {
                        float v = acc[i][j][r];
                        const float vp = __shfl_xor(v, 1);   // pair partner column
                        const float ang = (float)tokpos[(t0 + r) & (SEQ - 1)] * inv;
                        const float c = cosf(ang), s = sinf(ang);
                        v = (d & 1) ? (vp * s + v * c) : (v * c - vp * s);
                        dst[(size_t)(t0 + r) * D_MODEL + col] = (__bf16)v;
                    }
                }
            }
        }
    }
}

// ---------------------------------------------------------------------------
// Causal flash attention. 256 threads = 4 independent waves, each owning a
// 16-row q-tile (q0 = blockIdx.x*64 + wave*16). Q/K layout [token][h*64+d];
// V is per-head transposed Vt[bh*64+d][token] so PV B-fragments are
// contiguous bf16x8 loads. Per-wave private P buffer -> NO barriers.
// O aliases Q (each wave reads only its own rows, register-resident first).
// ---------------------------------------------------------------------------
__global__ __launch_bounds__(256) void attn_fused(
    const __bf16* Q, const __bf16* __restrict__ K,
    const __bf16* __restrict__ Vt, __bf16* O)
{
    const int tid  = threadIdx.x;
    const int wave = tid >> 6, lane = tid & 63;
    const int quad = lane >> 4, l16 = lane & 15;
    const int q0 = blockIdx.x * 64 + wave * 16;
    const int bh = blockIdx.y;
    const size_t base  = (size_t)(bh >> 4) * SEQ * D_MODEL + (size_t)(bh & 15) * HEAD_DIM;
    const size_t vbase = (size_t)bh * HEAD_DIM * SEQ;

    __shared__ __bf16 P[4][16][LDSP];   // per-wave private

    const __bf16* qrow = Q + base + (size_t)(q0 + l16) * D_MODEL + quad * 8;
    const bf16x8 a0 = *(const bf16x8*)(qrow);
    const bf16x8 a1 = *(const bf16x8*)(qrow + 32);

    float m_i[4], l_i[4];
    floatx4 o_acc[4] = {};   // [g][r]: row q0+quad*4+r, dim g*16+l16
#pragma unroll
    for (int r = 0; r < 4; ++r) { m_i[r] = -__builtin_inff(); l_i[r] = 0.f; }

    for (int k0 = 0; k0 <= q0 + 15; k0 += 32) {
        const __bf16* krow = K + base + (size_t)(k0 + l16) * D_MODEL + quad * 8;
        const bf16x8 b00 = *(const bf16x8*)(krow);
        const bf16x8 b01 = *(const bf16x8*)(krow + 32);
        const bf16x8 b10 = *(const bf16x8*)(krow + 16 * D_MODEL);
        const bf16x8 b11 = *(const bf16x8*)(krow + 16 * D_MODEL + 32);
        floatx4 s0 = {}, s1 = {};
        s0 = MFMA16(a0, b00, s0); s0 = MFMA16(a1, b01, s0);
        s1 = MFMA16(a0, b10, s1); s1 = MFMA16(a1, b11, s1);

        float p0a[4], p1a[4];
#pragma unroll
        for (int r = 0; r < 4; ++r) {
            const int qg = q0 + quad * 4 + r;
            float v0 = (k0 + l16 > qg)      ? -__builtin_inff() : s0[r] * 0.125f;
            float v1 = (k0 + 16 + l16 > qg) ? -__builtin_inff() : s1[r] * 0.125f;
            float mx = fmaxf(v0, v1);
#pragma unroll
            for (int off = 1; off < 16; off <<= 1) mx = fmaxf(mx, __shfl_xor(mx, off));
            const float m_new = fmaxf(m_i[r], mx);
            const float alpha = __expf(m_i[r] - m_new);
            const float p0 = __expf(v0 - m_new);
            const float p1 = __expf(v1 - m_new);
            float rs = p0 + p1;
#pragma unroll
            for (int off = 1; off < 16; off <<= 1) rs += __shfl_xor(rs, off);
            l_i[r] = l_i[r] * alpha + rs;
            m_i[r] = m_new;
#pragma unroll
            for (int g = 0; g < 4; ++g) o_acc[g][r] *= alpha;
            p0a[r] = p0; p1a[r] = p1;
        }

        // P: C-layout -> per-wave LDS -> A-layout (bf16). Same-wave RAW only;
        // compiler-inserted lgkmcnt waits are sufficient (no barriers).
#pragma unroll
        for (int r = 0; r < 4; ++r) {
            P[wave][quad * 4 + r][l16]      = (__bf16)p0a[r];
            P[wave][quad * 4 + r][16 + l16] = (__bf16)p1a[r];
        }
        const bf16x8 ap = *(const bf16x8*)&P[wave][l16][quad * 8];

        // PV: contiguous B-fragments from transposed V
#pragma unroll
        for (int g = 0; g < 4; ++g) {
            const bf16x8 vb = *(const bf16x8*)
                (Vt + vbase + (size_t)(g * 16 + l16) * SEQ + k0 + quad * 8);
            o_acc[g] = MFMA16(ap, vb, o_acc[g]);
        }
    }

#pragma unroll
    for (int g = 0; g < 4; ++g)
#pragma unroll
        for (int r = 0; r < 4; ++r) {
            const int t = q0 + quad * 4 + r;
            O[base + (size_t)t * D_MODEL + g * 16 + l16] = (__bf16)(o_acc[g][r] / l_i[r]);
        }
}

// ---------------------------------------------------------------------------
// ws layout (40 MB): Xb 8 | Wb (Wq,Wk,Wv,Wo cat) 8 | Qb 8 | Kb 8 | Vt 8.
// Attention output in-place over Qb. Inputs fp32, output fp32 (verified r5).
// ---------------------------------------------------------------------------
extern "C" void kernel_launch(void* const* d_in, const int* in_sizes, int n_in,
                              void* d_out, int out_size, void* d_ws, size_t ws_size,
                              hipStream_t stream) {
    const int* pos = (const int*)d_in[1];
    float* out = (float*)d_out;

    const size_t xe = (size_t)M_TOK * D_MODEL;      // 4M elements
    const size_t we = (size_t)D_MODEL * D_MODEL;    // 1M elements
    __bf16* Xb = (__bf16*)d_ws;
    __bf16* Wb = Xb + xe;          // 4M: [Wq | Wk | Wv | Wo]
    __bf16* Qb = Wb + 4 * we;
    __bf16* Kb = Qb + xe;
    __bf16* Vt = Kb + xe;          // [b*16+h][64][2048] transposed V

    // 1. fp32 -> bf16 conversions
    f32_to_bf16<<<(int)(xe / 8 / 256), 256, 0, stream>>>((const float*)d_in[0], Xb, (int)xe);
    f32_to_bf16<<<(int)(we / 8 / 256), 256, 0, stream>>>((const float*)d_in[2], Wb,          (int)we);
    f32_to_bf16<<<(int)(we / 8 / 256), 256, 0, stream>>>((const float*)d_in[3], Wb + we,     (int)we);
    f32_to_bf16<<<(int)(we / 8 / 256), 256, 0, stream>>>((const float*)d_in[4], Wb + 2 * we, (int)we);
    f32_to_bf16<<<(int)(we / 8 / 256), 256, 0, stream>>>((const float*)d_in[5], Wb + 3 * we, (int)we);

    // 2. fused QKV projection (+RoPE, V transposed): N = 3072
    gemm_tiled<0><<<dim3(M_TOK / 128, 3072 / 128), 256, 0, stream>>>(
        Xb, Wb, Qb, Kb, Vt, nullptr, pos);

    // 3. causal flash attention, in-place over Qb
    attn_fused<<<dim3(SEQ / 64, 2 * N_HEADS), 256, 0, stream>>>(Qb, Kb, Vt, Qb);

    // 4. output projection -> fp32 d_out
    gemm_tiled<1><<<dim3(M_TOK / 128, D_MODEL / 128), 256, 0, stream>>>(
        Qb, Wb + 3 * we, nullptr, nullptr, nullptr, out, pos);
}

// Round 7
// 832.918 us; speedup vs baseline: 1.0057x; 1.0057x over previous
//
#include <hip/hip_runtime.h>

typedef __bf16 bf16x4 __attribute__((ext_vector_type(4)));
typedef __bf16 bf16x8 __attribute__((ext_vector_type(8)));
typedef float floatx4 __attribute__((ext_vector_type(4)));

#define MFMA16(a, b, c) __builtin_amdgcn_mfma_f32_16x16x32_bf16((a), (b), (c), 0, 0, 0)

constexpr int D_MODEL = 1024;
constexpr int SEQ = 2048;
constexpr int HEAD_DIM = 64;
constexpr int M_TOK = 2 * SEQ;   // 4096 tokens (B=2)
constexpr int N_HEADS = 16;
constexpr float ROPE_C = 0.20762050593048596f;   // log2(10000)/64

// ---------------------------------------------------------------------------
// fp32 -> bf16 conversion prepass (n multiple of 8)
// ---------------------------------------------------------------------------
__global__ __launch_bounds__(256) void f32_to_bf16(const float* __restrict__ s,
                                                   __bf16* __restrict__ d, int n)
{
    const int i = (blockIdx.x * 256 + threadIdx.x) * 8;
    if (i >= n) return;
    const floatx4 lo = *(const floatx4*)(s + i);
    const floatx4 hi = *(const floatx4*)(s + i + 4);
    bf16x8 v;
    v[0] = (__bf16)lo[0]; v[1] = (__bf16)lo[1]; v[2] = (__bf16)lo[2]; v[3] = (__bf16)lo[3];
    v[4] = (__bf16)hi[0]; v[5] = (__bf16)hi[1]; v[6] = (__bf16)hi[2]; v[7] = (__bf16)hi[3];
    *(bf16x8*)(d + i) = v;
}

// ---------------------------------------------------------------------------
// Tiled GEMM: C[M][N] = A[M][1024] . B[N][1024]^T, bf16 in, 128x128 tile,
// 256 threads (4 waves, 2x2 of 64x64), BK=32.
// LDS: UNPADDED 64-B rows (m97-proven layout) -> every bf16x8 access is
// 16-B aligned. launch_bounds(256,2): 2 blocks/CU floor -> 256-reg budget,
// prevents the r6 catastrophic acc spill (VGPR=32, 1.65 GB scratch traffic).
// MODE 0: fused QKV epilogue (N=3072): n<1024 -> Qb (+RoPE), <2048 -> Kb
//         (+RoPE), else V written TRANSPOSED per head: Vt[bh*64+d][token].
// MODE 1: plain fp32 output (out projection).
// ---------------------------------------------------------------------------
template<int MODE>
__global__ __launch_bounds__(256, 2) void gemm_tiled(
    const __bf16* __restrict__ A, const __bf16* __restrict__ B,
    __bf16* __restrict__ Qb, __bf16* __restrict__ Kb, __bf16* __restrict__ Vt,
    float* __restrict__ Cf, const int* __restrict__ tokpos)
{
    __shared__ __bf16 As[128 * 32];   // [row][32], 8 KB, rows 64 B (16-B aligned)
    __shared__ __bf16 Bs[128 * 32];
    const int tid  = threadIdx.x;
    const int wave = tid >> 6, lane = tid & 63;
    const int quad = lane >> 4, l16 = lane & 15;
    const int m0 = blockIdx.x * 128, n0 = blockIdx.y * 128;
    const int wm = (wave >> 1) * 64, wn = (wave & 1) * 64;

    floatx4 acc[4][4] = {};

    for (int k0 = 0; k0 < D_MODEL; k0 += 32) {
        __syncthreads();   // protect previous iteration's fragment reads
#pragma unroll
        for (int r = 0; r < 2; ++r) {
            const int le = r * 2048 + tid * 8;       // 4096 elems per tile
            const int m = le >> 5, kk = le & 31;     // 4 lanes per 32-elem row
            *(bf16x8*)&As[m * 32 + kk] =
                *(const bf16x8*)(A + (size_t)(m0 + m) * D_MODEL + k0 + kk);
            *(bf16x8*)&Bs[m * 32 + kk] =
                *(const bf16x8*)(B + (size_t)(n0 + m) * D_MODEL + k0 + kk);
        }
        __syncthreads();

        bf16x8 af[4], bf[4];
#pragma unroll
        for (int i = 0; i < 4; ++i)
            af[i] = *(const bf16x8*)&As[(wm + i * 16 + l16) * 32 + quad * 8];
#pragma unroll
        for (int j = 0; j < 4; ++j)
            bf[j] = *(const bf16x8*)&Bs[(wn + j * 16 + l16) * 32 + quad * 8];
#pragma unroll
        for (int i = 0; i < 4; ++i)
#pragma unroll
            for (int j = 0; j < 4; ++j)
                acc[i][j] = MFMA16(af[i], bf[j], acc[i][j]);
    }

    // ---- epilogue ----
#pragma unroll
    for (int i = 0; i < 4; ++i) {
#pragma unroll
        for (int j = 0; j < 4; ++j) {
            const int n  = n0 + wn + j * 16 + l16;       // region-uniform per (i,j)
            const int t0 = m0 + wm + i * 16 + quad * 4;  // 4 consecutive tokens
            if (MODE == 1) {
#pragma unroll
                for (int r = 0; r < 4; ++r)
                    Cf[(size_t)(t0 + r) * D_MODEL + n] = acc[i][j][r];
            } else {
                const int region = n >> 10, col = n & 1023;
                if (region == 2) {
                    // V transposed: Vt[((b*16+h)*64+d)*SEQ + s]; row = b*1024+col
                    bf16x4 v;
#pragma unroll
                    for (int r = 0; r < 4; ++r) v[r] = (__bf16)acc[i][j][r];
                    const size_t vidx =
                        ((size_t)(t0 >> 11) * 1024 + col) * SEQ + (t0 & (SEQ - 1));
                    *(bf16x4*)(Vt + vidx) = v;
                } else {
                    const int d = col & (HEAD_DIM - 1);
                    const float inv = exp2f(-(float)(d & ~1) * ROPE_C);
                    __bf16* dst = (region == 0) ? Qb : Kb;
#pragma unroll
                    for (int r = 0; r < 4; ++r) {
                        float v = acc[i][j][r];
                        const float vp = __shfl_xor(v, 1);   // pair partner column
                        const float ang = (float)tokpos[(t0 + r) & (SEQ - 1)] * inv;
                        const float c = cosf(ang), s = sinf(ang);
                        v = (d & 1) ? (vp * s + v * c) : (v * c - vp * s);
                        dst[(size_t)(t0 + r) * D_MODEL + col] = (__bf16)v;
                    }
                }
            }
        }
    }
}

// ---------------------------------------------------------------------------
// Causal flash attention. 256 threads = 4 independent waves, each owning a
// 16-row q-tile (q0 = blockIdx.x*64 + wave*16). Q/K layout [token][h*64+d];
// V is per-head transposed Vt[bh*64+d][token] so PV B-fragments are
// contiguous bf16x8 loads. Per-wave private unpadded P (16-B aligned rows),
// no barriers. launch_bounds(256,4): 128-reg budget (kernel needs ~90),
// avoids the default occupancy-chasing reg cap. O aliases Q (in-place).
// ---------------------------------------------------------------------------
__global__ __launch_bounds__(256, 4) void attn_fused(
    const __bf16* Q, const __bf16* __restrict__ K,
    const __bf16* __restrict__ Vt, __bf16* O)
{
    const int tid  = threadIdx.x;
    const int wave = tid >> 6, lane = tid & 63;
    const int quad = lane >> 4, l16 = lane & 15;
    const int q0 = blockIdx.x * 64 + wave * 16;
    const int bh = blockIdx.y;
    const size_t base  = (size_t)(bh >> 4) * SEQ * D_MODEL + (size_t)(bh & 15) * HEAD_DIM;
    const size_t vbase = (size_t)bh * HEAD_DIM * SEQ;

    __shared__ __bf16 P[4][16][32];   // per-wave private, rows 64 B (aligned)

    const __bf16* qrow = Q + base + (size_t)(q0 + l16) * D_MODEL + quad * 8;
    const bf16x8 a0 = *(const bf16x8*)(qrow);
    const bf16x8 a1 = *(const bf16x8*)(qrow + 32);

    float m_i[4], l_i[4];
    floatx4 o_acc[4] = {};   // [g][r]: row q0+quad*4+r, dim g*16+l16
#pragma unroll
    for (int r = 0; r < 4; ++r) { m_i[r] = -__builtin_inff(); l_i[r] = 0.f; }

    for (int k0 = 0; k0 <= q0 + 15; k0 += 32) {
        const __bf16* krow = K + base + (size_t)(k0 + l16) * D_MODEL + quad * 8;
        const bf16x8 b00 = *(const bf16x8*)(krow);
        const bf16x8 b01 = *(const bf16x8*)(krow + 32);
        const bf16x8 b10 = *(const bf16x8*)(krow + 16 * D_MODEL);
        const bf16x8 b11 = *(const bf16x8*)(krow + 16 * D_MODEL + 32);
        floatx4 s0 = {}, s1 = {};
        s0 = MFMA16(a0, b00, s0); s0 = MFMA16(a1, b01, s0);
        s1 = MFMA16(a0, b10, s1); s1 = MFMA16(a1, b11, s1);

        float p0a[4], p1a[4];
#pragma unroll
        for (int r = 0; r < 4; ++r) {
            const int qg = q0 + quad * 4 + r;
            float v0 = (k0 + l16 > qg)      ? -__builtin_inff() : s0[r] * 0.125f;
            float v1 = (k0 + 16 + l16 > qg) ? -__builtin_inff() : s1[r] * 0.125f;
            float mx = fmaxf(v0, v1);
#pragma unroll
            for (int off = 1; off < 16; off <<= 1) mx = fmaxf(mx, __shfl_xor(mx, off));
            const float m_new = fmaxf(m_i[r], mx);
            const float alpha = __expf(m_i[r] - m_new);
            const float p0 = __expf(v0 - m_new);
            const float p1 = __expf(v1 - m_new);
            float rs = p0 + p1;
#pragma unroll
            for (int off = 1; off < 16; off <<= 1) rs += __shfl_xor(rs, off);
            l_i[r] = l_i[r] * alpha + rs;
            m_i[r] = m_new;
#pragma unroll
            for (int g = 0; g < 4; ++g) o_acc[g][r] *= alpha;
            p0a[r] = p0; p1a[r] = p1;
        }

        // P: C-layout -> per-wave LDS -> A-layout (bf16). Same-wave RAW only;
        // compiler-inserted lgkmcnt waits suffice (no barriers).
#pragma unroll
        for (int r = 0; r < 4; ++r) {
            P[wave][quad * 4 + r][l16]      = (__bf16)p0a[r];
            P[wave][quad * 4 + r][16 + l16] = (__bf16)p1a[r];
        }
        const bf16x8 ap = *(const bf16x8*)&P[wave][l16][quad * 8];

        // PV: contiguous B-fragments from transposed V
#pragma unroll
        for (int g = 0; g < 4; ++g) {
            const bf16x8 vb = *(const bf16x8*)
                (Vt + vbase + (size_t)(g * 16 + l16) * SEQ + k0 + quad * 8);
            o_acc[g] = MFMA16(ap, vb, o_acc[g]);
        }
    }

#pragma unroll
    for (int g = 0; g < 4; ++g)
#pragma unroll
        for (int r = 0; r < 4; ++r) {
            const int t = q0 + quad * 4 + r;
            O[base + (size_t)t * D_MODEL + g * 16 + l16] = (__bf16)(o_acc[g][r] / l_i[r]);
        }
}

// ---------------------------------------------------------------------------
// ws layout (40 MB): Xb 8 | Wb (Wq,Wk,Wv,Wo cat) 8 | Qb 8 | Kb 8 | Vt 8.
// Attention output in-place over Qb. Inputs fp32, output fp32 (verified r5).
// ---------------------------------------------------------------------------
extern "C" void kernel_launch(void* const* d_in, const int* in_sizes, int n_in,
                              void* d_out, int out_size, void* d_ws, size_t ws_size,
                              hipStream_t stream) {
    const int* pos = (const int*)d_in[1];
    float* out = (float*)d_out;

    const size_t xe = (size_t)M_TOK * D_MODEL;      // 4M elements
    const size_t we = (size_t)D_MODEL * D_MODEL;    // 1M elements
    __bf16* Xb = (__bf16*)d_ws;
    __bf16* Wb = Xb + xe;          // 4M: [Wq | Wk | Wv | Wo]
    __bf16* Qb = Wb + 4 * we;
    __bf16* Kb = Qb + xe;
    __bf16* Vt = Kb + xe;          // [b*16+h][64][2048] transposed V

    // 1. fp32 -> bf16 conversions
    f32_to_bf16<<<(int)(xe / 8 / 256), 256, 0, stream>>>((const float*)d_in[0], Xb, (int)xe);
    f32_to_bf16<<<(int)(we / 8 / 256), 256, 0, stream>>>((const float*)d_in[2], Wb,          (int)we);
    f32_to_bf16<<<(int)(we / 8 / 256), 256, 0, stream>>>((const float*)d_in[3], Wb + we,     (int)we);
    f32_to_bf16<<<(int)(we / 8 / 256), 256, 0, stream>>>((const float*)d_in[4], Wb + 2 * we, (int)we);
    f32_to_bf16<<<(int)(we / 8 / 256), 256, 0, stream>>>((const float*)d_in[5], Wb + 3 * we, (int)we);

    // 2. fused QKV projection (+RoPE, V transposed): N = 3072
    gemm_tiled<0><<<dim3(M_TOK / 128, 3072 / 128), 256, 0, stream>>>(
        Xb, Wb, Qb, Kb, Vt, nullptr, pos);

    // 3. causal flash attention, in-place over Qb
    attn_fused<<<dim3(SEQ / 64, 2 * N_HEADS), 256, 0, stream>>>(Qb, Kb, Vt, Qb);

    // 4. output projection -> fp32 d_out
    gemm_tiled<1><<<dim3(M_TOK / 128, D_MODEL / 128), 256, 0, stream>>>(
        Qb, Wb + 3 * we, nullptr, nullptr, nullptr, out, pos);
}

// Round 8
// 389.390 us; speedup vs baseline: 2.1513x; 2.1390x over previous
//
#include <hip/hip_runtime.h>

typedef __bf16 bf16x4 __attribute__((ext_vector_type(4)));
typedef __bf16 bf16x8 __attribute__((ext_vector_type(8)));
typedef float floatx4 __attribute__((ext_vector_type(4)));

#define MFMA16(a, b, c) __builtin_amdgcn_mfma_f32_16x16x32_bf16((a), (b), (c), 0, 0, 0)

constexpr int D_MODEL = 1024;
constexpr int SEQ = 2048;
constexpr int HEAD_DIM = 64;
constexpr int M_TOK = 2 * SEQ;   // 4096 tokens (B=2)
constexpr int N_HEADS = 16;
constexpr float ROPE_C = 0.20762050593048596f;   // log2(10000)/64

// ---------------------------------------------------------------------------
// Single-dispatch fp32 -> bf16 conversion of x + 4 weights into the
// contiguous ws region [Xb | Wq | Wk | Wv | Wo] (8M elements).
// ---------------------------------------------------------------------------
__global__ __launch_bounds__(256) void convert_all(
    const float* __restrict__ x,  const float* __restrict__ wq,
    const float* __restrict__ wk, const float* __restrict__ wv,
    const float* __restrict__ wo, __bf16* __restrict__ dst)
{
    const size_t i = ((size_t)blockIdx.x * 256 + threadIdx.x) * 8;   // < 8M
    const float* s;
    size_t off;
    if (i < 4194304) { s = x; off = i; }
    else {
        const int w = (int)((i - 4194304) >> 20);
        off = (i - 4194304) & 1048575;
        s = (w == 0) ? wq : (w == 1) ? wk : (w == 2) ? wv : wo;
    }
    const floatx4 lo = *(const floatx4*)(s + off);
    const floatx4 hi = *(const floatx4*)(s + off + 4);
    bf16x8 v;
    v[0] = (__bf16)lo[0]; v[1] = (__bf16)lo[1]; v[2] = (__bf16)lo[2]; v[3] = (__bf16)lo[3];
    v[4] = (__bf16)hi[0]; v[5] = (__bf16)hi[1]; v[6] = (__bf16)hi[2]; v[7] = (__bf16)hi[3];
    *(bf16x8*)(dst + i) = v;
}

// ---------------------------------------------------------------------------
// Tiled GEMM: C[M][N] = A[M][1024] . B[N][1024]^T, bf16 in, 128x128 tile,
// 256 threads (4 waves, 2x2 of 64x64), BK=32, unpadded 64-B LDS rows.
// Accumulators are 16 NAMED floatx4 variables — r6/r7 showed the compiler
// keeps the acc[4][4] ARRAY in scratch (VGPR_Count=32, 1.61 GB spill traffic
// = 768 blk x 256 thr x 32 iters x 256 B, immune to launch_bounds) — flat
// named vars make register allocation unavoidable.
// MODE 0: fused QKV epilogue (N=3072): n<1024 -> Qb (+RoPE), <2048 -> Kb
//         (+RoPE), else V TRANSPOSED per head: Vt[bh*64+d][token].
// MODE 1: plain fp32 output (out projection).
// ---------------------------------------------------------------------------
template<int MODE>
__global__ __launch_bounds__(256, 2) void gemm_tiled(
    const __bf16* __restrict__ A, const __bf16* __restrict__ B,
    __bf16* __restrict__ Qb, __bf16* __restrict__ Kb, __bf16* __restrict__ Vt,
    float* __restrict__ Cf, const int* __restrict__ tokpos)
{
    __shared__ __bf16 As[128 * 32];   // 8 KB, rows 64 B (16-B aligned)
    __shared__ __bf16 Bs[128 * 32];
    const int tid  = threadIdx.x;
    const int wave = tid >> 6, lane = tid & 63;
    const int quad = lane >> 4, l16 = lane & 15;
    const int m0 = blockIdx.x * 128, n0 = blockIdx.y * 128;
    const int wm = (wave >> 1) * 64, wn = (wave & 1) * 64;

    floatx4 c00 = {}, c01 = {}, c02 = {}, c03 = {};
    floatx4 c10 = {}, c11 = {}, c12 = {}, c13 = {};
    floatx4 c20 = {}, c21 = {}, c22 = {}, c23 = {};
    floatx4 c30 = {}, c31 = {}, c32 = {}, c33 = {};

    const int sm = tid >> 2;              // 0..63: row pair base (tid/4)
    const int sk = (tid & 3) * 8;         // 0,8,16,24
    const __bf16* gA = A + (size_t)(m0 + sm) * D_MODEL + sk;
    const __bf16* gB = B + (size_t)(n0 + sm) * D_MODEL + sk;

    for (int k0 = 0; k0 < D_MODEL; k0 += 32) {
        __syncthreads();   // protect previous iteration's fragment reads
        *(bf16x8*)&As[sm * 32 + sk]        = *(const bf16x8*)(gA + k0);
        *(bf16x8*)&As[(sm + 64) * 32 + sk] = *(const bf16x8*)(gA + (size_t)64 * D_MODEL + k0);
        *(bf16x8*)&Bs[sm * 32 + sk]        = *(const bf16x8*)(gB + k0);
        *(bf16x8*)&Bs[(sm + 64) * 32 + sk] = *(const bf16x8*)(gB + (size_t)64 * D_MODEL + k0);
        __syncthreads();

        const bf16x8 a0 = *(const bf16x8*)&As[(wm      + l16) * 32 + quad * 8];
        const bf16x8 a1 = *(const bf16x8*)&As[(wm + 16 + l16) * 32 + quad * 8];
        const bf16x8 a2 = *(const bf16x8*)&As[(wm + 32 + l16) * 32 + quad * 8];
        const bf16x8 a3 = *(const bf16x8*)&As[(wm + 48 + l16) * 32 + quad * 8];
        const bf16x8 b0 = *(const bf16x8*)&Bs[(wn      + l16) * 32 + quad * 8];
        const bf16x8 b1 = *(const bf16x8*)&Bs[(wn + 16 + l16) * 32 + quad * 8];
        const bf16x8 b2 = *(const bf16x8*)&Bs[(wn + 32 + l16) * 32 + quad * 8];
        const bf16x8 b3 = *(const bf16x8*)&Bs[(wn + 48 + l16) * 32 + quad * 8];

        c00 = MFMA16(a0, b0, c00); c01 = MFMA16(a0, b1, c01);
        c02 = MFMA16(a0, b2, c02); c03 = MFMA16(a0, b3, c03);
        c10 = MFMA16(a1, b0, c10); c11 = MFMA16(a1, b1, c11);
        c12 = MFMA16(a1, b2, c12); c13 = MFMA16(a1, b3, c13);
        c20 = MFMA16(a2, b0, c20); c21 = MFMA16(a2, b1, c21);
        c22 = MFMA16(a2, b2, c22); c23 = MFMA16(a2, b3, c23);
        c30 = MFMA16(a3, b0, c30); c31 = MFMA16(a3, b1, c31);
        c32 = MFMA16(a3, b2, c32); c33 = MFMA16(a3, b3, c33);
    }

    // ---- epilogue (per 16x16 sub-tile; I=row group, J=col group) ----
#define EPI(I, J, CV) do {                                                     \
        const int n  = n0 + wn + (J) * 16 + l16;                               \
        const int t0 = m0 + wm + (I) * 16 + quad * 4;                          \
        if (MODE == 1) {                                                       \
            Cf[(size_t)(t0 + 0) * D_MODEL + n] = (CV)[0];                      \
            Cf[(size_t)(t0 + 1) * D_MODEL + n] = (CV)[1];                      \
            Cf[(size_t)(t0 + 2) * D_MODEL + n] = (CV)[2];                      \
            Cf[(size_t)(t0 + 3) * D_MODEL + n] = (CV)[3];                      \
        } else {                                                               \
            const int region = n >> 10, col = n & 1023;                        \
            if (region == 2) {                                                 \
                bf16x4 v;                                                      \
                v[0] = (__bf16)(CV)[0]; v[1] = (__bf16)(CV)[1];                \
                v[2] = (__bf16)(CV)[2]; v[3] = (__bf16)(CV)[3];                \
                const size_t vidx =                                            \
                    ((size_t)(t0 >> 11) * 1024 + col) * SEQ + (t0 & (SEQ - 1));\
                *(bf16x4*)(Vt + vidx) = v;                                     \
            } else {                                                           \
                const int d = col & (HEAD_DIM - 1);                            \
                const float inv = exp2f(-(float)(d & ~1) * ROPE_C);            \
                __bf16* dst = (region == 0) ? Qb : Kb;                         \
                _Pragma("unroll")                                              \
                for (int r = 0; r < 4; ++r) {                                  \
                    float v = (CV)[r];                                         \
                    const float vp = __shfl_xor(v, 1);                         \
                    const float ang = (float)tokpos[(t0 + r) & (SEQ - 1)] * inv;\
                    const float cth = cosf(ang), sth = sinf(ang);              \
                    v = (d & 1) ? (vp * sth + v * cth) : (v * cth - vp * sth); \
                    dst[(size_t)(t0 + r) * D_MODEL + col] = (__bf16)v;         \
                }                                                              \
            }                                                                  \
        }                                                                      \
    } while (0)

    EPI(0, 0, c00); EPI(0, 1, c01); EPI(0, 2, c02); EPI(0, 3, c03);
    EPI(1, 0, c10); EPI(1, 1, c11); EPI(1, 2, c12); EPI(1, 3, c13);
    EPI(2, 0, c20); EPI(2, 1, c21); EPI(2, 2, c22); EPI(2, 3, c23);
    EPI(3, 0, c30); EPI(3, 1, c31); EPI(3, 2, c32); EPI(3, 3, c33);
#undef EPI
}

// ---------------------------------------------------------------------------
// Causal flash attention (unchanged from r7 — correct; revisit once it is
// the top dispatch). 4 independent waves/block, 16 q-rows each; V transposed;
// per-wave private P, no barriers; O aliases Q in-place.
// ---------------------------------------------------------------------------
__global__ __launch_bounds__(256, 4) void attn_fused(
    const __bf16* Q, const __bf16* __restrict__ K,
    const __bf16* __restrict__ Vt, __bf16* O)
{
    const int tid  = threadIdx.x;
    const int wave = tid >> 6, lane = tid & 63;
    const int quad = lane >> 4, l16 = lane & 15;
    const int q0 = blockIdx.x * 64 + wave * 16;
    const int bh = blockIdx.y;
    const size_t base  = (size_t)(bh >> 4) * SEQ * D_MODEL + (size_t)(bh & 15) * HEAD_DIM;
    const size_t vbase = (size_t)bh * HEAD_DIM * SEQ;

    __shared__ __bf16 P[4][16][32];   // per-wave private, rows 64 B (aligned)

    const __bf16* qrow = Q + base + (size_t)(q0 + l16) * D_MODEL + quad * 8;
    const bf16x8 a0 = *(const bf16x8*)(qrow);
    const bf16x8 a1 = *(const bf16x8*)(qrow + 32);

    float m_i[4], l_i[4];
    floatx4 o0 = {}, o1 = {}, o2 = {}, o3 = {};   // dim g*16+l16, row quad*4+r
#pragma unroll
    for (int r = 0; r < 4; ++r) { m_i[r] = -__builtin_inff(); l_i[r] = 0.f; }

    for (int k0 = 0; k0 <= q0 + 15; k0 += 32) {
        const __bf16* krow = K + base + (size_t)(k0 + l16) * D_MODEL + quad * 8;
        const bf16x8 b00 = *(const bf16x8*)(krow);
        const bf16x8 b01 = *(const bf16x8*)(krow + 32);
        const bf16x8 b10 = *(const bf16x8*)(krow + 16 * D_MODEL);
        const bf16x8 b11 = *(const bf16x8*)(krow + 16 * D_MODEL + 32);
        floatx4 s0 = {}, s1 = {};
        s0 = MFMA16(a0, b00, s0); s0 = MFMA16(a1, b01, s0);
        s1 = MFMA16(a0, b10, s1); s1 = MFMA16(a1, b11, s1);

        float p0a[4], p1a[4];
#pragma unroll
        for (int r = 0; r < 4; ++r) {
            const int qg = q0 + quad * 4 + r;
            float v0 = (k0 + l16 > qg)      ? -__builtin_inff() : s0[r] * 0.125f;
            float v1 = (k0 + 16 + l16 > qg) ? -__builtin_inff() : s1[r] * 0.125f;
            float mx = fmaxf(v0, v1);
#pragma unroll
            for (int off = 1; off < 16; off <<= 1) mx = fmaxf(mx, __shfl_xor(mx, off));
            const float m_new = fmaxf(m_i[r], mx);
            const float alpha = __expf(m_i[r] - m_new);
            const float p0 = __expf(v0 - m_new);
            const float p1 = __expf(v1 - m_new);
            float rs = p0 + p1;
#pragma unroll
            for (int off = 1; off < 16; off <<= 1) rs += __shfl_xor(rs, off);
            l_i[r] = l_i[r] * alpha + rs;
            m_i[r] = m_new;
            o0[r] *= alpha; o1[r] *= alpha; o2[r] *= alpha; o3[r] *= alpha;
            p0a[r] = p0; p1a[r] = p1;
        }

        // P: C-layout -> per-wave LDS -> A-layout (bf16); same-wave RAW only.
#pragma unroll
        for (int r = 0; r < 4; ++r) {
            P[wave][quad * 4 + r][l16]      = (__bf16)p0a[r];
            P[wave][quad * 4 + r][16 + l16] = (__bf16)p1a[r];
        }
        const bf16x8 ap = *(const bf16x8*)&P[wave][l16][quad * 8];

        const __bf16* vp = Vt + vbase + (size_t)l16 * SEQ + k0 + quad * 8;
        o0 = MFMA16(ap, *(const bf16x8*)(vp),                      o0);
        o1 = MFMA16(ap, *(const bf16x8*)(vp + (size_t)16 * SEQ),   o1);
        o2 = MFMA16(ap, *(const bf16x8*)(vp + (size_t)32 * SEQ),   o2);
        o3 = MFMA16(ap, *(const bf16x8*)(vp + (size_t)48 * SEQ),   o3);
    }

#pragma unroll
    for (int r = 0; r < 4; ++r) {
        const int t = q0 + quad * 4 + r;
        __bf16* orow = O + base + (size_t)t * D_MODEL + l16;
        orow[0]  = (__bf16)(o0[r] / l_i[r]);
        orow[16] = (__bf16)(o1[r] / l_i[r]);
        orow[32] = (__bf16)(o2[r] / l_i[r]);
        orow[48] = (__bf16)(o3[r] / l_i[r]);
    }
}

// ---------------------------------------------------------------------------
// ws layout (40 MB): Xb 8 | Wb (Wq,Wk,Wv,Wo cat) 8 | Qb 8 | Kb 8 | Vt 8.
// Attention output in-place over Qb. Inputs fp32, output fp32 (verified r5).
// ---------------------------------------------------------------------------
extern "C" void kernel_launch(void* const* d_in, const int* in_sizes, int n_in,
                              void* d_out, int out_size, void* d_ws, size_t ws_size,
                              hipStream_t stream) {
    const int* pos = (const int*)d_in[1];
    float* out = (float*)d_out;

    const size_t xe = (size_t)M_TOK * D_MODEL;      // 4M elements
    const size_t we = (size_t)D_MODEL * D_MODEL;    // 1M elements
    __bf16* Xb = (__bf16*)d_ws;
    __bf16* Wb = Xb + xe;          // [Wq | Wk | Wv | Wo]
    __bf16* Qb = Wb + 4 * we;
    __bf16* Kb = Qb + xe;
    __bf16* Vt = Kb + xe;          // [b*16+h][64][2048] transposed V

    // 1. one-dispatch fp32 -> bf16 conversion (8M elements, contiguous dst)
    convert_all<<<4096, 256, 0, stream>>>(
        (const float*)d_in[0], (const float*)d_in[2], (const float*)d_in[3],
        (const float*)d_in[4], (const float*)d_in[5], Xb);

    // 2. fused QKV projection (+RoPE, V transposed): N = 3072
    gemm_tiled<0><<<dim3(M_TOK / 128, 3072 / 128), 256, 0, stream>>>(
        Xb, Wb, Qb, Kb, Vt, nullptr, pos);

    // 3. causal flash attention, in-place over Qb
    attn_fused<<<dim3(SEQ / 64, 2 * N_HEADS), 256, 0, stream>>>(Qb, Kb, Vt, Qb);

    // 4. output projection -> fp32 d_out
    gemm_tiled<1><<<dim3(M_TOK / 128, D_MODEL / 128), 256, 0, stream>>>(
        Qb, Wb + 3 * we, nullptr, nullptr, nullptr, out, pos);
}

// Round 9
// 308.784 us; speedup vs baseline: 2.7129x; 1.2610x over previous
//
#include <hip/hip_runtime.h>

typedef __bf16 bf16x4 __attribute__((ext_vector_type(4)));
typedef __bf16 bf16x8 __attribute__((ext_vector_type(8)));
typedef float floatx4 __attribute__((ext_vector_type(4)));

#define MFMA16(a, b, c) __builtin_amdgcn_mfma_f32_16x16x32_bf16((a), (b), (c), 0, 0, 0)

constexpr int D_MODEL = 1024;
constexpr int SEQ = 2048;
constexpr int HEAD_DIM = 64;
constexpr int M_TOK = 2 * SEQ;   // 4096 tokens (B=2)
constexpr int N_HEADS = 16;
constexpr float ROPE_C = 0.20762050593048596f;   // log2(10000)/64

// ---------------------------------------------------------------------------
// Single-dispatch fp32 -> bf16 conversion of x + 4 weights into the
// contiguous ws region [Xb | Wq | Wk | Wv | Wo] (8M elements).
// ---------------------------------------------------------------------------
__global__ __launch_bounds__(256) void convert_all(
    const float* __restrict__ x,  const float* __restrict__ wq,
    const float* __restrict__ wk, const float* __restrict__ wv,
    const float* __restrict__ wo, __bf16* __restrict__ dst)
{
    const size_t i = ((size_t)blockIdx.x * 256 + threadIdx.x) * 8;   // < 8M
    const float* s;
    size_t off;
    if (i < 4194304) { s = x; off = i; }
    else {
        const int w = (int)((i - 4194304) >> 20);
        off = (i - 4194304) & 1048575;
        s = (w == 0) ? wq : (w == 1) ? wk : (w == 2) ? wv : wo;
    }
    const floatx4 lo = *(const floatx4*)(s + off);
    const floatx4 hi = *(const floatx4*)(s + off + 4);
    bf16x8 v;
    v[0] = (__bf16)lo[0]; v[1] = (__bf16)lo[1]; v[2] = (__bf16)lo[2]; v[3] = (__bf16)lo[3];
    v[4] = (__bf16)hi[0]; v[5] = (__bf16)hi[1]; v[6] = (__bf16)hi[2]; v[7] = (__bf16)hi[3];
    *(bf16x8*)(dst + i) = v;
}

// ---------------------------------------------------------------------------
// Tiled GEMM (unchanged from r8 — spill fixed by 16 NAMED floatx4 accs).
// 128x128 tile, 4 waves, BK=32, unpadded 64-B LDS rows.
// MODE 0: fused QKV epilogue (N=3072); MODE 1: fp32 out projection.
// ---------------------------------------------------------------------------
template<int MODE>
__global__ __launch_bounds__(256, 2) void gemm_tiled(
    const __bf16* __restrict__ A, const __bf16* __restrict__ B,
    __bf16* __restrict__ Qb, __bf16* __restrict__ Kb, __bf16* __restrict__ Vt,
    float* __restrict__ Cf, const int* __restrict__ tokpos)
{
    __shared__ __bf16 As[128 * 32];
    __shared__ __bf16 Bs[128 * 32];
    const int tid  = threadIdx.x;
    const int wave = tid >> 6, lane = tid & 63;
    const int quad = lane >> 4, l16 = lane & 15;
    const int m0 = blockIdx.x * 128, n0 = blockIdx.y * 128;
    const int wm = (wave >> 1) * 64, wn = (wave & 1) * 64;

    floatx4 c00 = {}, c01 = {}, c02 = {}, c03 = {};
    floatx4 c10 = {}, c11 = {}, c12 = {}, c13 = {};
    floatx4 c20 = {}, c21 = {}, c22 = {}, c23 = {};
    floatx4 c30 = {}, c31 = {}, c32 = {}, c33 = {};

    const int sm = tid >> 2;
    const int sk = (tid & 3) * 8;
    const __bf16* gA = A + (size_t)(m0 + sm) * D_MODEL + sk;
    const __bf16* gB = B + (size_t)(n0 + sm) * D_MODEL + sk;

    for (int k0 = 0; k0 < D_MODEL; k0 += 32) {
        __syncthreads();
        *(bf16x8*)&As[sm * 32 + sk]        = *(const bf16x8*)(gA + k0);
        *(bf16x8*)&As[(sm + 64) * 32 + sk] = *(const bf16x8*)(gA + (size_t)64 * D_MODEL + k0);
        *(bf16x8*)&Bs[sm * 32 + sk]        = *(const bf16x8*)(gB + k0);
        *(bf16x8*)&Bs[(sm + 64) * 32 + sk] = *(const bf16x8*)(gB + (size_t)64 * D_MODEL + k0);
        __syncthreads();

        const bf16x8 a0 = *(const bf16x8*)&As[(wm      + l16) * 32 + quad * 8];
        const bf16x8 a1 = *(const bf16x8*)&As[(wm + 16 + l16) * 32 + quad * 8];
        const bf16x8 a2 = *(const bf16x8*)&As[(wm + 32 + l16) * 32 + quad * 8];
        const bf16x8 a3 = *(const bf16x8*)&As[(wm + 48 + l16) * 32 + quad * 8];
        const bf16x8 b0 = *(const bf16x8*)&Bs[(wn      + l16) * 32 + quad * 8];
        const bf16x8 b1 = *(const bf16x8*)&Bs[(wn + 16 + l16) * 32 + quad * 8];
        const bf16x8 b2 = *(const bf16x8*)&Bs[(wn + 32 + l16) * 32 + quad * 8];
        const bf16x8 b3 = *(const bf16x8*)&Bs[(wn + 48 + l16) * 32 + quad * 8];

        c00 = MFMA16(a0, b0, c00); c01 = MFMA16(a0, b1, c01);
        c02 = MFMA16(a0, b2, c02); c03 = MFMA16(a0, b3, c03);
        c10 = MFMA16(a1, b0, c10); c11 = MFMA16(a1, b1, c11);
        c12 = MFMA16(a1, b2, c12); c13 = MFMA16(a1, b3, c13);
        c20 = MFMA16(a2, b0, c20); c21 = MFMA16(a2, b1, c21);
        c22 = MFMA16(a2, b2, c22); c23 = MFMA16(a2, b3, c23);
        c30 = MFMA16(a3, b0, c30); c31 = MFMA16(a3, b1, c31);
        c32 = MFMA16(a3, b2, c32); c33 = MFMA16(a3, b3, c33);
    }

#define EPI(I, J, CV) do {                                                     \
        const int n  = n0 + wn + (J) * 16 + l16;                               \
        const int t0 = m0 + wm + (I) * 16 + quad * 4;                          \
        if (MODE == 1) {                                                       \
            Cf[(size_t)(t0 + 0) * D_MODEL + n] = (CV)[0];                      \
            Cf[(size_t)(t0 + 1) * D_MODEL + n] = (CV)[1];                      \
            Cf[(size_t)(t0 + 2) * D_MODEL + n] = (CV)[2];                      \
            Cf[(size_t)(t0 + 3) * D_MODEL + n] = (CV)[3];                      \
        } else {                                                               \
            const int region = n >> 10, col = n & 1023;                        \
            if (region == 2) {                                                 \
                bf16x4 v;                                                      \
                v[0] = (__bf16)(CV)[0]; v[1] = (__bf16)(CV)[1];                \
                v[2] = (__bf16)(CV)[2]; v[3] = (__bf16)(CV)[3];                \
                const size_t vidx =                                            \
                    ((size_t)(t0 >> 11) * 1024 + col) * SEQ + (t0 & (SEQ - 1));\
                *(bf16x4*)(Vt + vidx) = v;                                     \
            } else {                                                           \
                const int d = col & (HEAD_DIM - 1);                            \
                const float inv = exp2f(-(float)(d & ~1) * ROPE_C);            \
                __bf16* dst = (region == 0) ? Qb : Kb;                         \
                _Pragma("unroll")                                              \
                for (int r = 0; r < 4; ++r) {                                  \
                    float v = (CV)[r];                                         \
                    const float vp = __shfl_xor(v, 1);                         \
                    const float ang = (float)tokpos[(t0 + r) & (SEQ - 1)] * inv;\
                    const float cth = cosf(ang), sth = sinf(ang);              \
                    v = (d & 1) ? (vp * sth + v * cth) : (v * cth - vp * sth); \
                    dst[(size_t)(t0 + r) * D_MODEL + col] = (__bf16)v;         \
                }                                                              \
            }                                                                  \
        }                                                                      \
    } while (0)

    EPI(0, 0, c00); EPI(0, 1, c01); EPI(0, 2, c02); EPI(0, 3, c03);
    EPI(1, 0, c10); EPI(1, 1, c11); EPI(1, 2, c12); EPI(1, 3, c13);
    EPI(2, 0, c20); EPI(2, 1, c21); EPI(2, 2, c22); EPI(2, 3, c23);
    EPI(3, 0, c30); EPI(3, 1, c31); EPI(3, 2, c32); EPI(3, 3, c33);
#undef EPI
}

// ---------------------------------------------------------------------------
// Causal flash attention v2.
// r8 counters: 237 us, MfmaUtil 2.9%, VALUBusy 15%, 82% idle (latency-bound).
// Fix 1 — balance: with grid (32 x-tiles, 32 bh) every CU got 4 blocks of the
//   SAME causal tile (256 = 0 mod 32) -> 2x imbalance. Now block bx's waves
//   handle mirrored tiles {2bx, 2bx+1, 127-2bx, 126-2bx}: per-block work is
//   exactly constant, covering all 128 tiles.
// Fix 2 — pipeline: prefetch next iter's K fragments at loop top; V loads
//   issued before softmax (independent of P) -> K/V latency hides behind
//   softmax + PV of the current iteration.
// ---------------------------------------------------------------------------
__global__ __launch_bounds__(256, 4) void attn_fused(
    const __bf16* Q, const __bf16* __restrict__ K,
    const __bf16* __restrict__ Vt, __bf16* O)
{
    const int tid  = threadIdx.x;
    const int wave = tid >> 6, lane = tid & 63;
    const int quad = lane >> 4, l16 = lane & 15;
    const int tsel = (wave < 2) ? (blockIdx.x * 2 + wave)
                                : (127 - (blockIdx.x * 2 + (wave - 2)));
    const int q0 = tsel * 16;
    const int bh = blockIdx.y;
    const size_t base  = (size_t)(bh >> 4) * SEQ * D_MODEL + (size_t)(bh & 15) * HEAD_DIM;
    const size_t vbase = (size_t)bh * HEAD_DIM * SEQ;
    const __bf16* kbase = K + base;

    __shared__ __bf16 P[4][16][32];   // per-wave private, rows 64 B (aligned)

    const __bf16* qrow = Q + base + (size_t)(q0 + l16) * D_MODEL + quad * 8;
    const bf16x8 a0 = *(const bf16x8*)(qrow);
    const bf16x8 a1 = *(const bf16x8*)(qrow + 32);

    float m_i[4], l_i[4];
    floatx4 o0 = {}, o1 = {}, o2 = {}, o3 = {};
#pragma unroll
    for (int r = 0; r < 4; ++r) { m_i[r] = -__builtin_inff(); l_i[r] = 0.f; }

    const int kend = q0 + 15;

    // preload K fragments for k0 = 0
    const __bf16* kr0 = kbase + (size_t)l16 * D_MODEL + quad * 8;
    bf16x8 kb00 = *(const bf16x8*)(kr0);
    bf16x8 kb01 = *(const bf16x8*)(kr0 + 32);
    bf16x8 kb10 = *(const bf16x8*)(kr0 + 16 * D_MODEL);
    bf16x8 kb11 = *(const bf16x8*)(kr0 + 16 * D_MODEL + 32);

    for (int k0 = 0; k0 <= kend; k0 += 32) {
        // ---- V loads for THIS iter (independent of softmax/P) ----
        const __bf16* vp = Vt + vbase + (size_t)l16 * SEQ + k0 + quad * 8;
        const bf16x8 v0 = *(const bf16x8*)(vp);
        const bf16x8 v1 = *(const bf16x8*)(vp + (size_t)16 * SEQ);
        const bf16x8 v2 = *(const bf16x8*)(vp + (size_t)32 * SEQ);
        const bf16x8 v3 = *(const bf16x8*)(vp + (size_t)48 * SEQ);

        // ---- prefetch NEXT iter's K fragments ----
        const int kn = (k0 + 32 <= kend) ? (k0 + 32) : k0;
        const __bf16* krow = kbase + (size_t)(kn + l16) * D_MODEL + quad * 8;
        const bf16x8 n00 = *(const bf16x8*)(krow);
        const bf16x8 n01 = *(const bf16x8*)(krow + 32);
        const bf16x8 n10 = *(const bf16x8*)(krow + 16 * D_MODEL);
        const bf16x8 n11 = *(const bf16x8*)(krow + 16 * D_MODEL + 32);

        // ---- scores with CURRENT K fragments (already resident) ----
        floatx4 s0 = {}, s1 = {};
        s0 = MFMA16(a0, kb00, s0); s0 = MFMA16(a1, kb01, s0);
        s1 = MFMA16(a0, kb10, s1); s1 = MFMA16(a1, kb11, s1);

        // ---- online softmax over 32 columns ----
        float p0a[4], p1a[4];
#pragma unroll
        for (int r = 0; r < 4; ++r) {
            const int qg = q0 + quad * 4 + r;
            float v0s = (k0 + l16 > qg)      ? -__builtin_inff() : s0[r] * 0.125f;
            float v1s = (k0 + 16 + l16 > qg) ? -__builtin_inff() : s1[r] * 0.125f;
            float mx = fmaxf(v0s, v1s);
#pragma unroll
            for (int off = 1; off < 16; off <<= 1) mx = fmaxf(mx, __shfl_xor(mx, off));
            const float m_new = fmaxf(m_i[r], mx);
            const float alpha = __expf(m_i[r] - m_new);
            const float p0 = __expf(v0s - m_new);
            const float p1 = __expf(v1s - m_new);
            float rs = p0 + p1;
#pragma unroll
            for (int off = 1; off < 16; off <<= 1) rs += __shfl_xor(rs, off);
            l_i[r] = l_i[r] * alpha + rs;
            m_i[r] = m_new;
            o0[r] *= alpha; o1[r] *= alpha; o2[r] *= alpha; o3[r] *= alpha;
            p0a[r] = p0; p1a[r] = p1;
        }

        // ---- P: C-layout -> per-wave LDS -> A-layout (same-wave RAW) ----
#pragma unroll
        for (int r = 0; r < 4; ++r) {
            P[wave][quad * 4 + r][l16]      = (__bf16)p0a[r];
            P[wave][quad * 4 + r][16 + l16] = (__bf16)p1a[r];
        }
        const bf16x8 ap = *(const bf16x8*)&P[wave][l16][quad * 8];

        // ---- PV (V already in flight/resident) ----
        o0 = MFMA16(ap, v0, o0);
        o1 = MFMA16(ap, v1, o1);
        o2 = MFMA16(ap, v2, o2);
        o3 = MFMA16(ap, v3, o3);

        // rotate prefetched K
        kb00 = n00; kb01 = n01; kb10 = n10; kb11 = n11;
    }

#pragma unroll
    for (int r = 0; r < 4; ++r) {
        const float rl = 1.0f / l_i[r];
        const int t = q0 + quad * 4 + r;
        __bf16* orow = O + base + (size_t)t * D_MODEL + l16;
        orow[0]  = (__bf16)(o0[r] * rl);
        orow[16] = (__bf16)(o1[r] * rl);
        orow[32] = (__bf16)(o2[r] * rl);
        orow[48] = (__bf16)(o3[r] * rl);
    }
}

// ---------------------------------------------------------------------------
// ws layout (40 MB): Xb 8 | Wb (Wq,Wk,Wv,Wo cat) 8 | Qb 8 | Kb 8 | Vt 8.
// Attention output in-place over Qb. Inputs fp32, output fp32.
// ---------------------------------------------------------------------------
extern "C" void kernel_launch(void* const* d_in, const int* in_sizes, int n_in,
                              void* d_out, int out_size, void* d_ws, size_t ws_size,
                              hipStream_t stream) {
    const int* pos = (const int*)d_in[1];
    float* out = (float*)d_out;

    const size_t xe = (size_t)M_TOK * D_MODEL;      // 4M elements
    const size_t we = (size_t)D_MODEL * D_MODEL;    // 1M elements
    __bf16* Xb = (__bf16*)d_ws;
    __bf16* Wb = Xb + xe;          // [Wq | Wk | Wv | Wo]
    __bf16* Qb = Wb + 4 * we;
    __bf16* Kb = Qb + xe;
    __bf16* Vt = Kb + xe;          // [b*16+h][64][2048] transposed V

    convert_all<<<4096, 256, 0, stream>>>(
        (const float*)d_in[0], (const float*)d_in[2], (const float*)d_in[3],
        (const float*)d_in[4], (const float*)d_in[5], Xb);

    gemm_tiled<0><<<dim3(M_TOK / 128, 3072 / 128), 256, 0, stream>>>(
        Xb, Wb, Qb, Kb, Vt, nullptr, pos);

    // mirrored-tile grid: 32 x-blocks cover 128 q-tiles (4 per block)
    attn_fused<<<dim3(SEQ / 64, 2 * N_HEADS), 256, 0, stream>>>(Qb, Kb, Vt, Qb);

    gemm_tiled<1><<<dim3(M_TOK / 128, D_MODEL / 128), 256, 0, stream>>>(
        Qb, Wb + 3 * we, nullptr, nullptr, nullptr, out, pos);
}

// Round 10
// 284.600 us; speedup vs baseline: 2.9435x; 1.0850x over previous
//
#include <hip/hip_runtime.h>

typedef __bf16 bf16x4 __attribute__((ext_vector_type(4)));
typedef __bf16 bf16x8 __attribute__((ext_vector_type(8)));
typedef float floatx4 __attribute__((ext_vector_type(4)));

#define MFMA16(a, b, c) __builtin_amdgcn_mfma_f32_16x16x32_bf16((a), (b), (c), 0, 0, 0)

constexpr int D_MODEL = 1024;
constexpr int SEQ = 2048;
constexpr int HEAD_DIM = 64;
constexpr int M_TOK = 2 * SEQ;   // 4096 tokens (B=2)
constexpr int N_HEADS = 16;
constexpr float ROPE_C = 0.20762050593048596f;   // log2(10000)/64

// ---------------------------------------------------------------------------
// Single-dispatch fp32 -> bf16 conversion of x + 4 weights into the
// contiguous ws region [Xb | Wq | Wk | Wv | Wo] (8M elements).
// ---------------------------------------------------------------------------
__global__ __launch_bounds__(256) void convert_all(
    const float* __restrict__ x,  const float* __restrict__ wq,
    const float* __restrict__ wk, const float* __restrict__ wv,
    const float* __restrict__ wo, __bf16* __restrict__ dst)
{
    const size_t i = ((size_t)blockIdx.x * 256 + threadIdx.x) * 8;   // < 8M
    const float* s;
    size_t off;
    if (i < 4194304) { s = x; off = i; }
    else {
        const int w = (int)((i - 4194304) >> 20);
        off = (i - 4194304) & 1048575;
        s = (w == 0) ? wq : (w == 1) ? wk : (w == 2) ? wv : wo;
    }
    const floatx4 lo = *(const floatx4*)(s + off);
    const floatx4 hi = *(const floatx4*)(s + off + 4);
    bf16x8 v;
    v[0] = (__bf16)lo[0]; v[1] = (__bf16)lo[1]; v[2] = (__bf16)lo[2]; v[3] = (__bf16)lo[3];
    v[4] = (__bf16)hi[0]; v[5] = (__bf16)hi[1]; v[6] = (__bf16)hi[2]; v[7] = (__bf16)hi[3];
    *(bf16x8*)(dst + i) = v;
}

// ---------------------------------------------------------------------------
// Tiled GEMM (unchanged from r8/r9). 128x128 tile, 4 waves, BK=32.
// MODE 0: fused QKV epilogue (N=3072); MODE 1: fp32 out projection.
// ---------------------------------------------------------------------------
template<int MODE>
__global__ __launch_bounds__(256, 2) void gemm_tiled(
    const __bf16* __restrict__ A, const __bf16* __restrict__ B,
    __bf16* __restrict__ Qb, __bf16* __restrict__ Kb, __bf16* __restrict__ Vt,
    float* __restrict__ Cf, const int* __restrict__ tokpos)
{
    __shared__ __bf16 As[128 * 32];
    __shared__ __bf16 Bs[128 * 32];
    const int tid  = threadIdx.x;
    const int wave = tid >> 6, lane = tid & 63;
    const int quad = lane >> 4, l16 = lane & 15;
    const int m0 = blockIdx.x * 128, n0 = blockIdx.y * 128;
    const int wm = (wave >> 1) * 64, wn = (wave & 1) * 64;

    floatx4 c00 = {}, c01 = {}, c02 = {}, c03 = {};
    floatx4 c10 = {}, c11 = {}, c12 = {}, c13 = {};
    floatx4 c20 = {}, c21 = {}, c22 = {}, c23 = {};
    floatx4 c30 = {}, c31 = {}, c32 = {}, c33 = {};

    const int sm = tid >> 2;
    const int sk = (tid & 3) * 8;
    const __bf16* gA = A + (size_t)(m0 + sm) * D_MODEL + sk;
    const __bf16* gB = B + (size_t)(n0 + sm) * D_MODEL + sk;

    for (int k0 = 0; k0 < D_MODEL; k0 += 32) {
        __syncthreads();
        *(bf16x8*)&As[sm * 32 + sk]        = *(const bf16x8*)(gA + k0);
        *(bf16x8*)&As[(sm + 64) * 32 + sk] = *(const bf16x8*)(gA + (size_t)64 * D_MODEL + k0);
        *(bf16x8*)&Bs[sm * 32 + sk]        = *(const bf16x8*)(gB + k0);
        *(bf16x8*)&Bs[(sm + 64) * 32 + sk] = *(const bf16x8*)(gB + (size_t)64 * D_MODEL + k0);
        __syncthreads();

        const bf16x8 a0 = *(const bf16x8*)&As[(wm      + l16) * 32 + quad * 8];
        const bf16x8 a1 = *(const bf16x8*)&As[(wm + 16 + l16) * 32 + quad * 8];
        const bf16x8 a2 = *(const bf16x8*)&As[(wm + 32 + l16) * 32 + quad * 8];
        const bf16x8 a3 = *(const bf16x8*)&As[(wm + 48 + l16) * 32 + quad * 8];
        const bf16x8 b0 = *(const bf16x8*)&Bs[(wn      + l16) * 32 + quad * 8];
        const bf16x8 b1 = *(const bf16x8*)&Bs[(wn + 16 + l16) * 32 + quad * 8];
        const bf16x8 b2 = *(const bf16x8*)&Bs[(wn + 32 + l16) * 32 + quad * 8];
        const bf16x8 b3 = *(const bf16x8*)&Bs[(wn + 48 + l16) * 32 + quad * 8];

        c00 = MFMA16(a0, b0, c00); c01 = MFMA16(a0, b1, c01);
        c02 = MFMA16(a0, b2, c02); c03 = MFMA16(a0, b3, c03);
        c10 = MFMA16(a1, b0, c10); c11 = MFMA16(a1, b1, c11);
        c12 = MFMA16(a1, b2, c12); c13 = MFMA16(a1, b3, c13);
        c20 = MFMA16(a2, b0, c20); c21 = MFMA16(a2, b1, c21);
        c22 = MFMA16(a2, b2, c22); c23 = MFMA16(a2, b3, c23);
        c30 = MFMA16(a3, b0, c30); c31 = MFMA16(a3, b1, c31);
        c32 = MFMA16(a3, b2, c32); c33 = MFMA16(a3, b3, c33);
    }

#define EPI(I, J, CV) do {                                                     \
        const int n  = n0 + wn + (J) * 16 + l16;                               \
        const int t0 = m0 + wm + (I) * 16 + quad * 4;                          \
        if (MODE == 1) {                                                       \
            Cf[(size_t)(t0 + 0) * D_MODEL + n] = (CV)[0];                      \
            Cf[(size_t)(t0 + 1) * D_MODEL + n] = (CV)[1];                      \
            Cf[(size_t)(t0 + 2) * D_MODEL + n] = (CV)[2];                      \
            Cf[(size_t)(t0 + 3) * D_MODEL + n] = (CV)[3];                      \
        } else {                                                               \
            const int region = n >> 10, col = n & 1023;                        \
            if (region == 2) {                                                 \
                bf16x4 v;                                                      \
                v[0] = (__bf16)(CV)[0]; v[1] = (__bf16)(CV)[1];                \
                v[2] = (__bf16)(CV)[2]; v[3] = (__bf16)(CV)[3];                \
                const size_t vidx =                                            \
                    ((size_t)(t0 >> 11) * 1024 + col) * SEQ + (t0 & (SEQ - 1));\
                *(bf16x4*)(Vt + vidx) = v;                                     \
            } else {                                                           \
                const int d = col & (HEAD_DIM - 1);                            \
                const float inv = exp2f(-(float)(d & ~1) * ROPE_C);            \
                __bf16* dst = (region == 0) ? Qb : Kb;                         \
                _Pragma("unroll")                                              \
                for (int r = 0; r < 4; ++r) {                                  \
                    float v = (CV)[r];                                         \
                    const float vp = __shfl_xor(v, 1);                         \
                    const float ang = (float)tokpos[(t0 + r) & (SEQ - 1)] * inv;\
                    const float cth = cosf(ang), sth = sinf(ang);              \
                    v = (d & 1) ? (vp * sth + v * cth) : (v * cth - vp * sth); \
                    dst[(size_t)(t0 + r) * D_MODEL + col] = (__bf16)v;         \
                }                                                              \
            }                                                                  \
        }                                                                      \
    } while (0)

    EPI(0, 0, c00); EPI(0, 1, c01); EPI(0, 2, c02); EPI(0, 3, c03);
    EPI(1, 0, c10); EPI(1, 1, c11); EPI(1, 2, c12); EPI(1, 3, c13);
    EPI(2, 0, c20); EPI(2, 1, c21); EPI(2, 2, c22); EPI(2, 3, c23);
    EPI(3, 0, c30); EPI(3, 1, c31); EPI(3, 2, c32); EPI(3, 3, c33);
#undef EPI
}

// ---------------------------------------------------------------------------
// Causal flash attention v3 — TRANSPOSED score tiles.
// S^T = K.Q^T (A=K-frag, B=Q-frag: same loads as v2, operands swapped), so
// queries sit on lanes (col=l16) and keys on regs/quads:
//   * per-query softmax state (m,l,alpha) is a per-lane SCALAR,
//   * max/sum over 32 keys = 7 reg-ops + 2 shuffles (vs 32 shuffle-pairs),
//   * causal mask only needed in the FINAL k-block (split loop),
//   * scale folded into exp args: p = exp((v-m)*0.125)  (softmax-invariant).
// PV as O^T = V^T.P^T: A=Vt-frag (same loads), B=P^T via per-wave LDS
// (rows padded to 40 elems: writes max 2-way/free, reads 16-B aligned).
// Epilogue stores packed bf16x4. Mirrored tile balance + K prefetch kept.
// O aliases Q (in-place, same-rows-only as before).
// ---------------------------------------------------------------------------
__global__ __launch_bounds__(256, 4) void attn_fused(
    const __bf16* Q, const __bf16* __restrict__ K,
    const __bf16* __restrict__ Vt, __bf16* O)
{
    const int tid  = threadIdx.x;
    const int wave = tid >> 6, lane = tid & 63;
    const int quad = lane >> 4, l16 = lane & 15;
    const int tsel = (wave < 2) ? (blockIdx.x * 2 + wave)
                                : (127 - (blockIdx.x * 2 + (wave - 2)));
    const int q0 = tsel * 16;
    const int bh = blockIdx.y;
    const size_t base  = (size_t)(bh >> 4) * SEQ * D_MODEL + (size_t)(bh & 15) * HEAD_DIM;
    const size_t vbase = (size_t)bh * HEAD_DIM * SEQ;
    const __bf16* kbase = K + base;

    __shared__ __bf16 P[4][16][40];   // per-wave; [query l16][key 0..31], pad 40

    // Q as B-operand: lane n=l16 -> query row q0+l16
    const __bf16* qrow = Q + base + (size_t)(q0 + l16) * D_MODEL + quad * 8;
    const bf16x8 qf0 = *(const bf16x8*)(qrow);
    const bf16x8 qf1 = *(const bf16x8*)(qrow + 32);

    float m_i = -__builtin_inff(), l_i = 0.f;          // per-query (lane) scalars
    floatx4 o0 = {}, o1 = {}, o2 = {}, o3 = {};        // O^T: dim g*16+quad*4+r, query l16

    // K as A-operand: lane m=l16 -> key row; preload k0 = 0
    const __bf16* kr0 = kbase + (size_t)l16 * D_MODEL + quad * 8;
    bf16x8 kb00 = *(const bf16x8*)(kr0);
    bf16x8 kb01 = *(const bf16x8*)(kr0 + 32);
    bf16x8 kb10 = *(const bf16x8*)(kr0 + 16 * D_MODEL);
    bf16x8 kb11 = *(const bf16x8*)(kr0 + 16 * D_MODEL + 32);

    const int klast = ((q0 + 15) >> 5) << 5;   // the single masked k-block

#define ATTN_STEP(K0, MASKED, PREFETCH)                                        \
    do {                                                                       \
        const __bf16* vp = Vt + vbase + (size_t)l16 * SEQ + (K0) + quad * 8;   \
        const bf16x8 v0 = *(const bf16x8*)(vp);                                \
        const bf16x8 v1 = *(const bf16x8*)(vp + (size_t)16 * SEQ);             \
        const bf16x8 v2 = *(const bf16x8*)(vp + (size_t)32 * SEQ);             \
        const bf16x8 v3 = *(const bf16x8*)(vp + (size_t)48 * SEQ);             \
        bf16x8 n00, n01, n10, n11;                                             \
        if (PREFETCH) {                                                        \
            const __bf16* krow = kbase + (size_t)((K0) + 32 + l16) * D_MODEL + quad * 8; \
            n00 = *(const bf16x8*)(krow);                                      \
            n01 = *(const bf16x8*)(krow + 32);                                 \
            n10 = *(const bf16x8*)(krow + 16 * D_MODEL);                       \
            n11 = *(const bf16x8*)(krow + 16 * D_MODEL + 32);                  \
        }                                                                      \
        floatx4 s0 = {}, s1 = {};                                              \
        s0 = MFMA16(kb00, qf0, s0); s0 = MFMA16(kb01, qf1, s0);                \
        s1 = MFMA16(kb10, qf0, s1); s1 = MFMA16(kb11, qf1, s1);                \
        if (MASKED) {                                                          \
            const int qg = q0 + l16;                                           \
            _Pragma("unroll")                                                  \
            for (int r = 0; r < 4; ++r) {                                      \
                if ((K0) + quad * 4 + r > qg)      s0[r] = -__builtin_inff();  \
                if ((K0) + 16 + quad * 4 + r > qg) s1[r] = -__builtin_inff();  \
            }                                                                  \
        }                                                                      \
        float mx = fmaxf(fmaxf(fmaxf(s0[0], s0[1]), fmaxf(s0[2], s0[3])),      \
                         fmaxf(fmaxf(s1[0], s1[1]), fmaxf(s1[2], s1[3])));     \
        mx = fmaxf(mx, __shfl_xor(mx, 16));                                    \
        mx = fmaxf(mx, __shfl_xor(mx, 32));                                    \
        const float m_new = fmaxf(m_i, mx);                                    \
        const float alpha = __expf((m_i - m_new) * 0.125f);                    \
        float p0[4], p1[4], rs = 0.f;                                          \
        _Pragma("unroll")                                                      \
        for (int r = 0; r < 4; ++r) {                                          \
            p0[r] = __expf((s0[r] - m_new) * 0.125f);                          \
            p1[r] = __expf((s1[r] - m_new) * 0.125f);                          \
            rs += p0[r] + p1[r];                                               \
        }                                                                      \
        rs += __shfl_xor(rs, 16);                                              \
        rs += __shfl_xor(rs, 32);                                              \
        l_i = l_i * alpha + rs;                                                \
        m_i = m_new;                                                           \
        o0 *= alpha; o1 *= alpha; o2 *= alpha; o3 *= alpha;                    \
        bf16x4 pw0, pw1;                                                       \
        _Pragma("unroll")                                                      \
        for (int r = 0; r < 4; ++r) { pw0[r] = (__bf16)p0[r]; pw1[r] = (__bf16)p1[r]; } \
        *(bf16x4*)&P[wave][l16][quad * 4]      = pw0;                          \
        *(bf16x4*)&P[wave][l16][16 + quad * 4] = pw1;                          \
        const bf16x8 pp = *(const bf16x8*)&P[wave][l16][quad * 8];             \
        o0 = MFMA16(v0, pp, o0);                                               \
        o1 = MFMA16(v1, pp, o1);                                               \
        o2 = MFMA16(v2, pp, o2);                                               \
        o3 = MFMA16(v3, pp, o3);                                               \
        if (PREFETCH) { kb00 = n00; kb01 = n01; kb10 = n10; kb11 = n11; }      \
    } while (0)

    for (int k0 = 0; k0 < klast; k0 += 32)
        ATTN_STEP(k0, false, true);     // unmasked body, prefetch next K
    ATTN_STEP(klast, true, false);      // final (only) masked block
#undef ATTN_STEP

    // ---- epilogue: O[token q0+l16][dim g*16+quad*4+r], packed bf16x4 ----
    const float rl = 1.0f / l_i;
    __bf16* orow = O + base + (size_t)(q0 + l16) * D_MODEL + quad * 4;
    bf16x4 w0, w1, w2, w3;
#pragma unroll
    for (int r = 0; r < 4; ++r) {
        w0[r] = (__bf16)(o0[r] * rl);
        w1[r] = (__bf16)(o1[r] * rl);
        w2[r] = (__bf16)(o2[r] * rl);
        w3[r] = (__bf16)(o3[r] * rl);
    }
    *(bf16x4*)(orow)      = w0;
    *(bf16x4*)(orow + 16) = w1;
    *(bf16x4*)(orow + 32) = w2;
    *(bf16x4*)(orow + 48) = w3;
}

// ---------------------------------------------------------------------------
// ws layout (40 MB): Xb 8 | Wb (Wq,Wk,Wv,Wo cat) 8 | Qb 8 | Kb 8 | Vt 8.
// Attention output in-place over Qb. Inputs fp32, output fp32.
// ---------------------------------------------------------------------------
extern "C" void kernel_launch(void* const* d_in, const int* in_sizes, int n_in,
                              void* d_out, int out_size, void* d_ws, size_t ws_size,
                              hipStream_t stream) {
    const int* pos = (const int*)d_in[1];
    float* out = (float*)d_out;

    const size_t xe = (size_t)M_TOK * D_MODEL;      // 4M elements
    const size_t we = (size_t)D_MODEL * D_MODEL;    // 1M elements
    __bf16* Xb = (__bf16*)d_ws;
    __bf16* Wb = Xb + xe;          // [Wq | Wk | Wv | Wo]
    __bf16* Qb = Wb + 4 * we;
    __bf16* Kb = Qb + xe;
    __bf16* Vt = Kb + xe;          // [b*16+h][64][2048] transposed V

    convert_all<<<4096, 256, 0, stream>>>(
        (const float*)d_in[0], (const float*)d_in[2], (const float*)d_in[3],
        (const float*)d_in[4], (const float*)d_in[5], Xb);

    gemm_tiled<0><<<dim3(M_TOK / 128, 3072 / 128), 256, 0, stream>>>(
        Xb, Wb, Qb, Kb, Vt, nullptr, pos);

    attn_fused<<<dim3(SEQ / 64, 2 * N_HEADS), 256, 0, stream>>>(Qb, Kb, Vt, Qb);

    gemm_tiled<1><<<dim3(M_TOK / 128, D_MODEL / 128), 256, 0, stream>>>(
        Qb, Wb + 3 * we, nullptr, nullptr, nullptr, out, pos);
}